// Round 2
// baseline (1350.717 us; speedup 1.0000x reference)
//
#include <hip/hip_runtime.h>

// Problem constants
#define BATCH 8
#define NPTS 1500         // N
#define DIM 256           // D
#define M1 1501           // NPTS+1 (couplings dim)
#define KSTRIDE 1504      // padded row stride for K matrix
#define MROWS 24000       // 2*B*N rows through the MLP
#define ITERS 50

__device__ __forceinline__ float4 ld4(const float* p){ return *(const float4*)p; }

// ---------------------------------------------------------------------------
// GEMM 1: H1 = relu([quer | pos_end or pos_start] @ W1 + b1)
// M=24000, K=512, N=256.  BM=128, BN=64, BK=16, 256 thr, 8x4 micro-tile.
// ---------------------------------------------------------------------------
__global__ __launch_bounds__(256) void mlp1_kernel(
    const float* __restrict__ quer, const float* __restrict__ pos_end,
    const float* __restrict__ pos_start, const float* __restrict__ W1,
    const float* __restrict__ b1, float* __restrict__ H)
{
  __shared__ float As[16][128];
  __shared__ float Bs[16][64];
  const int t = threadIdx.x;
  const int tm = t & 15, tn = t >> 4;
  const int m0 = blockIdx.x * 128, n0 = blockIdx.y * 64;
  float acc[8][4];
#pragma unroll
  for (int i = 0; i < 8; ++i)
#pragma unroll
    for (int j = 0; j < 4; ++j) acc[i][j] = 0.f;

  for (int kt = 0; kt < 512; kt += 16) {
#pragma unroll
    for (int it = 0; it < 2; ++it) {
      int s = t + it * 256;
      int m = s >> 2, kq = s & 3;
      int row = m0 + m;
      int col = kt + (kq << 2);
      float4 v = make_float4(0.f, 0.f, 0.f, 0.f);
      if (row < MROWS) {
        int r12 = (row < 12000) ? row : row - 12000;
        const float* src;
        if (col < 256) src = quer + (size_t)r12 * 256 + col;
        else src = ((row < 12000) ? pos_end : pos_start) + (size_t)r12 * 256 + (col - 256);
        v = ld4(src);
      }
      int kk = kq << 2;
      As[kk + 0][m] = v.x; As[kk + 1][m] = v.y; As[kk + 2][m] = v.z; As[kk + 3][m] = v.w;
    }
    {
      int kr = t >> 4, nq = t & 15;
      float4 w = ld4(W1 + (size_t)(kt + kr) * 256 + n0 + (nq << 2));
      *(float4*)&Bs[kr][nq << 2] = w;
    }
    __syncthreads();
#pragma unroll
    for (int k = 0; k < 16; ++k) {
      float4 a0 = *(float4*)&As[k][tm << 2];
      float4 a1 = *(float4*)&As[k][64 + (tm << 2)];
      float4 b  = *(float4*)&Bs[k][tn << 2];
      float am[8] = {a0.x, a0.y, a0.z, a0.w, a1.x, a1.y, a1.z, a1.w};
      float bn[4] = {b.x, b.y, b.z, b.w};
#pragma unroll
      for (int i = 0; i < 8; ++i)
#pragma unroll
        for (int j = 0; j < 4; ++j) acc[i][j] += am[i] * bn[j];
    }
    __syncthreads();
  }
  float4 bb = ld4(b1 + n0 + (tn << 2));
  float bn[4] = {bb.x, bb.y, bb.z, bb.w};
#pragma unroll
  for (int i = 0; i < 8; ++i) {
    int row = m0 + ((i < 4) ? ((tm << 2) + i) : (64 + (tm << 2) + i - 4));
    if (row < MROWS) {
      float4 o;
      o.x = fmaxf(acc[i][0] + bn[0], 0.f);
      o.y = fmaxf(acc[i][1] + bn[1], 0.f);
      o.z = fmaxf(acc[i][2] + bn[2], 0.f);
      o.w = fmaxf(acc[i][3] + bn[3], 0.f);
      *(float4*)&H[(size_t)row * 256 + n0 + (tn << 2)] = o;
    }
  }
}

// ---------------------------------------------------------------------------
// GEMM: out = act(A @ W + b), A:[M][256], W:[256][256]
// ---------------------------------------------------------------------------
template<int RELU>
__global__ __launch_bounds__(256) void gemm_bias_kernel(
    const float* __restrict__ A, const float* __restrict__ W,
    const float* __restrict__ bias, float* __restrict__ out, int M)
{
  __shared__ float As[16][128];
  __shared__ float Bs[16][64];
  const int t = threadIdx.x;
  const int tm = t & 15, tn = t >> 4;
  const int m0 = blockIdx.x * 128, n0 = blockIdx.y * 64;
  float acc[8][4];
#pragma unroll
  for (int i = 0; i < 8; ++i)
#pragma unroll
    for (int j = 0; j < 4; ++j) acc[i][j] = 0.f;

  for (int kt = 0; kt < 256; kt += 16) {
#pragma unroll
    for (int it = 0; it < 2; ++it) {
      int s = t + it * 256;
      int m = s >> 2, kq = s & 3;
      int row = m0 + m;
      int col = kt + (kq << 2);
      float4 v = make_float4(0.f, 0.f, 0.f, 0.f);
      if (row < M) v = ld4(A + (size_t)row * 256 + col);
      int kk = kq << 2;
      As[kk + 0][m] = v.x; As[kk + 1][m] = v.y; As[kk + 2][m] = v.z; As[kk + 3][m] = v.w;
    }
    {
      int kr = t >> 4, nq = t & 15;
      float4 w = ld4(W + (size_t)(kt + kr) * 256 + n0 + (nq << 2));
      *(float4*)&Bs[kr][nq << 2] = w;
    }
    __syncthreads();
#pragma unroll
    for (int k = 0; k < 16; ++k) {
      float4 a0 = *(float4*)&As[k][tm << 2];
      float4 a1 = *(float4*)&As[k][64 + (tm << 2)];
      float4 b  = *(float4*)&Bs[k][tn << 2];
      float am[8] = {a0.x, a0.y, a0.z, a0.w, a1.x, a1.y, a1.z, a1.w};
      float bn[4] = {b.x, b.y, b.z, b.w};
#pragma unroll
      for (int i = 0; i < 8; ++i)
#pragma unroll
        for (int j = 0; j < 4; ++j) acc[i][j] += am[i] * bn[j];
    }
    __syncthreads();
  }
  float4 bb = ld4(bias + n0 + (tn << 2));
  float bn[4] = {bb.x, bb.y, bb.z, bb.w};
#pragma unroll
  for (int i = 0; i < 8; ++i) {
    int row = m0 + ((i < 4) ? ((tm << 2) + i) : (64 + (tm << 2) + i - 4));
    if (row < M) {
      float4 o;
      o.x = acc[i][0] + bn[0]; o.y = acc[i][1] + bn[1];
      o.z = acc[i][2] + bn[2]; o.w = acc[i][3] + bn[3];
      if (RELU) { o.x = fmaxf(o.x, 0.f); o.y = fmaxf(o.y, 0.f); o.z = fmaxf(o.z, 0.f); o.w = fmaxf(o.w, 0.f); }
      *(float4*)&out[(size_t)row * 256 + n0 + (tn << 2)] = o;
    }
  }
}

// ---------------------------------------------------------------------------
// Scores: K[b][i][j] = exp(f1_i . f2_j / 16), diag -> 0.  A@B^T GEMM.
// F holds f1 rows [0,12000), f2 rows [12000,24000).
// ---------------------------------------------------------------------------
__global__ __launch_bounds__(256) void scores_kernel(
    const float* __restrict__ F, float* __restrict__ Kmat)
{
  __shared__ float As[16][128];
  __shared__ float Bs[16][64];
  const int t = threadIdx.x;
  const int tm = t & 15, tn = t >> 4;
  const int b = blockIdx.z;
  const int m0 = blockIdx.x * 128, n0 = blockIdx.y * 64;
  const float* F1 = F + (size_t)b * NPTS * 256;
  const float* F2 = F + (size_t)(12000 + b * NPTS) * 256;
  float* Kb = Kmat + (size_t)b * M1 * KSTRIDE;
  float acc[8][4];
#pragma unroll
  for (int i = 0; i < 8; ++i)
#pragma unroll
    for (int j = 0; j < 4; ++j) acc[i][j] = 0.f;

  for (int kt = 0; kt < 256; kt += 16) {
#pragma unroll
    for (int it = 0; it < 2; ++it) {
      int s = t + it * 256;
      int m = s >> 2, kq = s & 3;
      int row = m0 + m;
      float4 v = make_float4(0.f, 0.f, 0.f, 0.f);
      if (row < NPTS) v = ld4(F1 + (size_t)row * 256 + kt + (kq << 2));
      int kk = kq << 2;
      As[kk + 0][m] = v.x; As[kk + 1][m] = v.y; As[kk + 2][m] = v.z; As[kk + 3][m] = v.w;
    }
    {
      int n = t >> 2, kq = t & 3;
      float4 v = make_float4(0.f, 0.f, 0.f, 0.f);
      if (n0 + n < NPTS) v = ld4(F2 + (size_t)(n0 + n) * 256 + kt + (kq << 2));
      int kk = kq << 2;
      Bs[kk + 0][n] = v.x; Bs[kk + 1][n] = v.y; Bs[kk + 2][n] = v.z; Bs[kk + 3][n] = v.w;
    }
    __syncthreads();
#pragma unroll
    for (int k = 0; k < 16; ++k) {
      float4 a0 = *(float4*)&As[k][tm << 2];
      float4 a1 = *(float4*)&As[k][64 + (tm << 2)];
      float4 b4 = *(float4*)&Bs[k][tn << 2];
      float am[8] = {a0.x, a0.y, a0.z, a0.w, a1.x, a1.y, a1.z, a1.w};
      float bn[4] = {b4.x, b4.y, b4.z, b4.w};
#pragma unroll
      for (int i = 0; i < 8; ++i)
#pragma unroll
        for (int j = 0; j < 4; ++j) acc[i][j] += am[i] * bn[j];
    }
    __syncthreads();
  }
#pragma unroll
  for (int i = 0; i < 8; ++i) {
    int gi = m0 + ((i < 4) ? ((tm << 2) + i) : (64 + (tm << 2) + i - 4));
    if (gi < NPTS) {
#pragma unroll
      for (int j = 0; j < 4; ++j) {
        int gj = n0 + (tn << 2) + j;
        if (gj < NPTS) {
          float v = acc[i][j] * 0.0625f;   // / sqrt(256)
          Kb[(size_t)gi * KSTRIDE + gj] = (gi == gj) ? 0.f : expf(v);
        }
      }
    }
  }
}

// Fill bin row/col with exp(alpha); init ev = 1
__global__ void bins_kernel(float* __restrict__ Kmat, const float* __restrict__ palpha,
                            float* __restrict__ ev)
{
  int gid = blockIdx.x * 256 + threadIdx.x;
  if (gid >= BATCH * M1) return;
  int b = gid / M1, x = gid % M1;
  float E = expf(palpha[0]);
  float* Kb = Kmat + (size_t)b * M1 * KSTRIDE;
  Kb[(size_t)NPTS * KSTRIDE + x] = E;   // bin row
  Kb[(size_t)x * KSTRIDE + NPTS] = E;   // bin col (bin-bin covered, same value)
  ev[b * KSTRIDE + x] = 1.0f;           // v0 = 0  ->  ev = 1
}

// ---------------------------------------------------------------------------
// Sinkhorn phase 1 (rows): one K read per iteration.
// Grid 512 x 256: 64 blocks (=256 waves) per batch; wave handles rows
// i = wv, wv+256, ...  For each row: dot(K_i, ev) -> eu_i, and accumulate
// column partials acc_j += K_ij * eu_i in the SAME register-held row.
// 4 waves combine partials in LDS -> part[b][blk][j].
// ---------------------------------------------------------------------------
__global__ __launch_bounds__(256) void sink_rows_kernel(
    const float* __restrict__ Kmat, const float* __restrict__ ev,
    float* __restrict__ eu, float* __restrict__ part)
{
  const int t = threadIdx.x;
  const int wave = t >> 6, lane = t & 63;
  const int bk = blockIdx.x;
  const int bb = bk >> 6;          // batch
  const int rb = bk & 63;          // block-in-batch
  const int wv = (rb << 2) | wave; // wave-in-batch, 0..255
  const float* Kb = Kmat + (size_t)bb * M1 * KSTRIDE;
  const float* evb = ev + bb * KSTRIDE;
  float* eub = eu + bb * KSTRIDE;
  float* partb = part + (size_t)bb * 64 * KSTRIDE;
  __shared__ float smem[4][KSTRIDE];

  float acc[24];
#pragma unroll
  for (int k = 0; k < 24; ++k) acc[k] = 0.f;
  for (int i = wv; i < M1; i += 256) {
    const float* row = Kb + (size_t)i * KSTRIDE;
    float r[24];
    float dot = 0.f;
#pragma unroll
    for (int k = 0; k < 24; ++k) {
      int j = lane + (k << 6);
      float kv = (j < M1) ? row[j] : 0.f;
      float e  = (j < M1) ? evb[j] : 0.f;
      r[k] = kv;
      dot += kv * e;
    }
#pragma unroll
    for (int off = 32; off > 0; off >>= 1) dot += __shfl_xor(dot, off);
    float mu = (i < NPTS) ? (1.0f / 3000.0f) : 0.5f;
    float euv = mu / dot;
    if (lane == 0) eub[i] = euv;
#pragma unroll
    for (int k = 0; k < 24; ++k) acc[k] += r[k] * euv;
  }
#pragma unroll
  for (int k = 0; k < 24; ++k) {
    int j = lane + (k << 6);
    if (j < KSTRIDE) smem[wave][j] = acc[k];
  }
  __syncthreads();
  for (int j = t; j < M1; j += 256) {
    float s = smem[0][j] + smem[1][j] + smem[2][j] + smem[3][j];
    partb[(size_t)rb * KSTRIDE + j] = s;
  }
}

// Sinkhorn phase 2 (cols): reduce 64 partials -> ev
__global__ void sink_cols_kernel(const float* __restrict__ part,
                                 float* __restrict__ ev)
{
  int j = blockIdx.x * 256 + threadIdx.x;
  int bb = blockIdx.y;
  if (j >= M1) return;
  const float* partb = part + (size_t)bb * 64 * KSTRIDE;
  float c = 0.f;
#pragma unroll 8
  for (int p = 0; p < 64; ++p) c += partb[(size_t)p * KSTRIDE + j];
  float nu = (j < NPTS) ? (1.0f / 3000.0f) : 0.5f;
  ev[bb * KSTRIDE + j] = nu / c;
}

// out[b][i][j] = K * eu_i * ev_j * (m+n)
__global__ void finalize_kernel(const float* __restrict__ Kmat,
                                const float* __restrict__ eu,
                                const float* __restrict__ ev,
                                float* __restrict__ out)
{
  size_t gid = (size_t)blockIdx.x * 256 + threadIdx.x;
  const size_t total = (size_t)BATCH * M1 * M1;
  if (gid >= total) return;
  int b = (int)(gid / ((size_t)M1 * M1));
  int rem = (int)(gid % ((size_t)M1 * M1));
  int i = rem / M1, j = rem % M1;
  float v = Kmat[((size_t)b * M1 + i) * KSTRIDE + j] * eu[b * KSTRIDE + i] * ev[b * KSTRIDE + j];
  out[gid] = v * 3000.0f;
}

// ---------------------------------------------------------------------------
extern "C" void kernel_launch(void* const* d_in, const int* in_sizes, int n_in,
                              void* d_out, int out_size, void* d_ws, size_t ws_size,
                              hipStream_t stream)
{
  const float* quer      = (const float*)d_in[0];
  const float* pos_start = (const float*)d_in[1];
  const float* pos_end   = (const float*)d_in[2];
  const float* W1 = (const float*)d_in[3];
  const float* b1 = (const float*)d_in[4];
  const float* W2 = (const float*)d_in[5];
  const float* b2 = (const float*)d_in[6];
  const float* W3 = (const float*)d_in[7];
  const float* b3 = (const float*)d_in[8];
  const float* alpha = (const float*)d_in[9];

  char* ws = (char*)d_ws;
  size_t off = 0;
  auto carve = [&](size_t bytes) -> void* {
    void* p = ws + off;
    off += (bytes + 1023) & ~(size_t)1023;
    return p;
  };
  float* H1   = (float*)carve((size_t)MROWS * 256 * 4);          // 24.6 MB (also holds F)
  float* H2   = (float*)carve((size_t)MROWS * 256 * 4);          // 24.6 MB
  float* K    = (float*)carve((size_t)BATCH * M1 * KSTRIDE * 4); // 72.2 MB
  float* part = (float*)carve((size_t)BATCH * 64 * KSTRIDE * 4); // 3.1 MB
  float* eu   = (float*)carve((size_t)BATCH * KSTRIDE * 4);
  float* ev   = (float*)carve((size_t)BATCH * KSTRIDE * 4);
  (void)ws_size; (void)in_sizes; (void)n_in; (void)out_size;

  dim3 blk(256);
  // MLP: f1 rows [0,12000) use pos_end; f2 rows [12000,24000) use pos_start
  mlp1_kernel<<<dim3(188, 4), blk, 0, stream>>>(quer, pos_end, pos_start, W1, b1, H1);
  gemm_bias_kernel<1><<<dim3(188, 4), blk, 0, stream>>>(H1, W2, b2, H2, MROWS);
  gemm_bias_kernel<0><<<dim3(188, 4), blk, 0, stream>>>(H2, W3, b3, H1, MROWS);
  // scores -> K (exp domain), bins + ev init
  scores_kernel<<<dim3(12, 24, 8), blk, 0, stream>>>(H1, K);
  bins_kernel<<<dim3((BATCH * M1 + 255) / 256), blk, 0, stream>>>(K, alpha, ev);
  // sinkhorn: 50 x (rows -> cols), plain launches (stream order = sync)
  for (int it = 0; it < ITERS; ++it) {
    sink_rows_kernel<<<dim3(512), blk, 0, stream>>>(K, ev, eu, part);
    sink_cols_kernel<<<dim3(6, 8), blk, 0, stream>>>(part, ev);
  }
  // output
  {
    size_t total = (size_t)BATCH * M1 * M1;
    finalize_kernel<<<dim3((unsigned)((total + 255) / 256)), blk, 0, stream>>>(K, eu, ev, (float*)d_out);
  }
}

// Round 3
// 1268.752 us; speedup vs baseline: 1.0646x; 1.0646x over previous
//
#include <hip/hip_runtime.h>

// Problem constants
#define BATCH 8
#define NPTS 1500         // N
#define DIM 256           // D
#define M1 1501           // NPTS+1 (couplings dim)
#define KSTRIDE 1504      // padded row stride for K matrix (16B-aligned rows)
#define MROWS 24000       // 2*B*N rows through the MLP
#define ITERS 50
#define MU_PT (1.0f / 3000.0f)
#define MU_BIN 0.5f

__device__ __forceinline__ float4 ld4(const float* p){ return *(const float4*)p; }

// ---------------------------------------------------------------------------
// GEMM 1: H1 = relu([quer | pos_end or pos_start] @ W1 + b1)
// M=24000, K=512, N=256.  BM=128, BN=64, BK=16, 256 thr, 8x4 micro-tile.
// ---------------------------------------------------------------------------
__global__ __launch_bounds__(256) void mlp1_kernel(
    const float* __restrict__ quer, const float* __restrict__ pos_end,
    const float* __restrict__ pos_start, const float* __restrict__ W1,
    const float* __restrict__ b1, float* __restrict__ H)
{
  __shared__ float As[16][128];
  __shared__ float Bs[16][64];
  const int t = threadIdx.x;
  const int tm = t & 15, tn = t >> 4;
  const int m0 = blockIdx.x * 128, n0 = blockIdx.y * 64;
  float acc[8][4];
#pragma unroll
  for (int i = 0; i < 8; ++i)
#pragma unroll
    for (int j = 0; j < 4; ++j) acc[i][j] = 0.f;

  for (int kt = 0; kt < 512; kt += 16) {
#pragma unroll
    for (int it = 0; it < 2; ++it) {
      int s = t + it * 256;
      int m = s >> 2, kq = s & 3;
      int row = m0 + m;
      int col = kt + (kq << 2);
      float4 v = make_float4(0.f, 0.f, 0.f, 0.f);
      if (row < MROWS) {
        int r12 = (row < 12000) ? row : row - 12000;
        const float* src;
        if (col < 256) src = quer + (size_t)r12 * 256 + col;
        else src = ((row < 12000) ? pos_end : pos_start) + (size_t)r12 * 256 + (col - 256);
        v = ld4(src);
      }
      int kk = kq << 2;
      As[kk + 0][m] = v.x; As[kk + 1][m] = v.y; As[kk + 2][m] = v.z; As[kk + 3][m] = v.w;
    }
    {
      int kr = t >> 4, nq = t & 15;
      float4 w = ld4(W1 + (size_t)(kt + kr) * 256 + n0 + (nq << 2));
      *(float4*)&Bs[kr][nq << 2] = w;
    }
    __syncthreads();
#pragma unroll
    for (int k = 0; k < 16; ++k) {
      float4 a0 = *(float4*)&As[k][tm << 2];
      float4 a1 = *(float4*)&As[k][64 + (tm << 2)];
      float4 b  = *(float4*)&Bs[k][tn << 2];
      float am[8] = {a0.x, a0.y, a0.z, a0.w, a1.x, a1.y, a1.z, a1.w};
      float bn[4] = {b.x, b.y, b.z, b.w};
#pragma unroll
      for (int i = 0; i < 8; ++i)
#pragma unroll
        for (int j = 0; j < 4; ++j) acc[i][j] += am[i] * bn[j];
    }
    __syncthreads();
  }
  float4 bb = ld4(b1 + n0 + (tn << 2));
  float bn[4] = {bb.x, bb.y, bb.z, bb.w};
#pragma unroll
  for (int i = 0; i < 8; ++i) {
    int row = m0 + ((i < 4) ? ((tm << 2) + i) : (64 + (tm << 2) + i - 4));
    if (row < MROWS) {
      float4 o;
      o.x = fmaxf(acc[i][0] + bn[0], 0.f);
      o.y = fmaxf(acc[i][1] + bn[1], 0.f);
      o.z = fmaxf(acc[i][2] + bn[2], 0.f);
      o.w = fmaxf(acc[i][3] + bn[3], 0.f);
      *(float4*)&H[(size_t)row * 256 + n0 + (tn << 2)] = o;
    }
  }
}

// ---------------------------------------------------------------------------
// GEMM: out = act(A @ W + b), A:[M][256], W:[256][256]
// ---------------------------------------------------------------------------
template<int RELU>
__global__ __launch_bounds__(256) void gemm_bias_kernel(
    const float* __restrict__ A, const float* __restrict__ W,
    const float* __restrict__ bias, float* __restrict__ out, int M)
{
  __shared__ float As[16][128];
  __shared__ float Bs[16][64];
  const int t = threadIdx.x;
  const int tm = t & 15, tn = t >> 4;
  const int m0 = blockIdx.x * 128, n0 = blockIdx.y * 64;
  float acc[8][4];
#pragma unroll
  for (int i = 0; i < 8; ++i)
#pragma unroll
    for (int j = 0; j < 4; ++j) acc[i][j] = 0.f;

  for (int kt = 0; kt < 256; kt += 16) {
#pragma unroll
    for (int it = 0; it < 2; ++it) {
      int s = t + it * 256;
      int m = s >> 2, kq = s & 3;
      int row = m0 + m;
      int col = kt + (kq << 2);
      float4 v = make_float4(0.f, 0.f, 0.f, 0.f);
      if (row < M) v = ld4(A + (size_t)row * 256 + col);
      int kk = kq << 2;
      As[kk + 0][m] = v.x; As[kk + 1][m] = v.y; As[kk + 2][m] = v.z; As[kk + 3][m] = v.w;
    }
    {
      int kr = t >> 4, nq = t & 15;
      float4 w = ld4(W + (size_t)(kt + kr) * 256 + n0 + (nq << 2));
      *(float4*)&Bs[kr][nq << 2] = w;
    }
    __syncthreads();
#pragma unroll
    for (int k = 0; k < 16; ++k) {
      float4 a0 = *(float4*)&As[k][tm << 2];
      float4 a1 = *(float4*)&As[k][64 + (tm << 2)];
      float4 b  = *(float4*)&Bs[k][tn << 2];
      float am[8] = {a0.x, a0.y, a0.z, a0.w, a1.x, a1.y, a1.z, a1.w};
      float bn[4] = {b.x, b.y, b.z, b.w};
#pragma unroll
      for (int i = 0; i < 8; ++i)
#pragma unroll
        for (int j = 0; j < 4; ++j) acc[i][j] += am[i] * bn[j];
    }
    __syncthreads();
  }
  float4 bb = ld4(bias + n0 + (tn << 2));
  float bn[4] = {bb.x, bb.y, bb.z, bb.w};
#pragma unroll
  for (int i = 0; i < 8; ++i) {
    int row = m0 + ((i < 4) ? ((tm << 2) + i) : (64 + (tm << 2) + i - 4));
    if (row < M) {
      float4 o;
      o.x = acc[i][0] + bn[0]; o.y = acc[i][1] + bn[1];
      o.z = acc[i][2] + bn[2]; o.w = acc[i][3] + bn[3];
      if (RELU) { o.x = fmaxf(o.x, 0.f); o.y = fmaxf(o.y, 0.f); o.z = fmaxf(o.z, 0.f); o.w = fmaxf(o.w, 0.f); }
      *(float4*)&out[(size_t)row * 256 + n0 + (tn << 2)] = o;
    }
  }
}

// ---------------------------------------------------------------------------
// Scores: K[b][i][j] = exp(f1_i . f2_j / 16), diag -> 0.  A@B^T GEMM.
// F holds f1 rows [0,12000), f2 rows [12000,24000).
// ---------------------------------------------------------------------------
__global__ __launch_bounds__(256) void scores_kernel(
    const float* __restrict__ F, float* __restrict__ Kmat)
{
  __shared__ float As[16][128];
  __shared__ float Bs[16][64];
  const int t = threadIdx.x;
  const int tm = t & 15, tn = t >> 4;
  const int b = blockIdx.z;
  const int m0 = blockIdx.x * 128, n0 = blockIdx.y * 64;
  const float* F1 = F + (size_t)b * NPTS * 256;
  const float* F2 = F + (size_t)(12000 + b * NPTS) * 256;
  float* Kb = Kmat + (size_t)b * M1 * KSTRIDE;
  float acc[8][4];
#pragma unroll
  for (int i = 0; i < 8; ++i)
#pragma unroll
    for (int j = 0; j < 4; ++j) acc[i][j] = 0.f;

  for (int kt = 0; kt < 256; kt += 16) {
#pragma unroll
    for (int it = 0; it < 2; ++it) {
      int s = t + it * 256;
      int m = s >> 2, kq = s & 3;
      int row = m0 + m;
      float4 v = make_float4(0.f, 0.f, 0.f, 0.f);
      if (row < NPTS) v = ld4(F1 + (size_t)row * 256 + kt + (kq << 2));
      int kk = kq << 2;
      As[kk + 0][m] = v.x; As[kk + 1][m] = v.y; As[kk + 2][m] = v.z; As[kk + 3][m] = v.w;
    }
    {
      int n = t >> 2, kq = t & 3;
      float4 v = make_float4(0.f, 0.f, 0.f, 0.f);
      if (n0 + n < NPTS) v = ld4(F2 + (size_t)(n0 + n) * 256 + kt + (kq << 2));
      int kk = kq << 2;
      Bs[kk + 0][n] = v.x; Bs[kk + 1][n] = v.y; Bs[kk + 2][n] = v.z; Bs[kk + 3][n] = v.w;
    }
    __syncthreads();
#pragma unroll
    for (int k = 0; k < 16; ++k) {
      float4 a0 = *(float4*)&As[k][tm << 2];
      float4 a1 = *(float4*)&As[k][64 + (tm << 2)];
      float4 b4 = *(float4*)&Bs[k][tn << 2];
      float am[8] = {a0.x, a0.y, a0.z, a0.w, a1.x, a1.y, a1.z, a1.w};
      float bn[4] = {b4.x, b4.y, b4.z, b4.w};
#pragma unroll
      for (int i = 0; i < 8; ++i)
#pragma unroll
        for (int j = 0; j < 4; ++j) acc[i][j] += am[i] * bn[j];
    }
    __syncthreads();
  }
#pragma unroll
  for (int i = 0; i < 8; ++i) {
    int gi = m0 + ((i < 4) ? ((tm << 2) + i) : (64 + (tm << 2) + i - 4));
    if (gi < NPTS) {
#pragma unroll
      for (int j = 0; j < 4; ++j) {
        int gj = n0 + (tn << 2) + j;
        if (gj < NPTS) {
          float v = acc[i][j] * 0.0625f;   // / sqrt(256)
          Kb[(size_t)gi * KSTRIDE + gj] = (gi == gj) ? 0.f : expf(v);
        }
      }
    }
  }
}

// ---------------------------------------------------------------------------
// bins: fill bin row/col with exp(alpha); zero K pad columns; zero csum0.
// gid over BATCH*KSTRIDE.
// ---------------------------------------------------------------------------
__global__ void bins_kernel(float* __restrict__ Kmat, const float* __restrict__ palpha,
                            float* __restrict__ csum0)
{
  int gid = blockIdx.x * 256 + threadIdx.x;
  if (gid >= BATCH * KSTRIDE) return;
  int b = gid / KSTRIDE, x = gid % KSTRIDE;
  float E = expf(palpha[0]);
  float* Kb = Kmat + (size_t)b * M1 * KSTRIDE;
  csum0[gid] = 0.f;
  if (x < M1) {
    Kb[(size_t)NPTS * KSTRIDE + x] = E;   // bin row
    Kb[(size_t)x * KSTRIDE + NPTS] = E;   // bin col (bin-bin covered, same value)
    // zero pad columns of this row so float4 loads see clean zeros
    Kb[(size_t)x * KSTRIDE + 1501] = 0.f;
    Kb[(size_t)x * KSTRIDE + 1502] = 0.f;
    Kb[(size_t)x * KSTRIDE + 1503] = 0.f;
  } else {
    Kb[(size_t)NPTS * KSTRIDE + x] = 0.f; // pad of bin row
  }
}

// ---------------------------------------------------------------------------
// Fused Sinkhorn iteration, ONE dispatch per iteration.
// Grid 512 x 256: 64 blocks (=256 waves) per batch.
//  A) each block: ev[j] = nu_j / csum_prev[j] into LDS (6 KB read)
//     block rb==0 zeros csum_zero (the it+1 buffer; untouched by others)
//  B) per wave, rows i = wv, wv+256, ...: float4-load row (held in regs),
//     dot with LDS ev -> eu_i = mu_i/dot; accumulate col partials r*eu.
//  C) 4 waves combine in LDS; 6 atomicAdds/thread into csum_cur.
// Triple-buffered csum: read prev, accumulate cur, zero next.
// ---------------------------------------------------------------------------
__global__ __launch_bounds__(256) void sink_iter_kernel(
    const float* __restrict__ Kmat,
    const float* __restrict__ csum_prev,
    float* __restrict__ csum_cur,
    float* __restrict__ csum_zero,
    float* __restrict__ eu, int first)
{
  const int t = threadIdx.x;
  const int wave = t >> 6, lane = t & 63;
  const int bk = blockIdx.x;
  const int bb = bk >> 6;          // batch
  const int rb = bk & 63;          // block-in-batch
  const int wv = (rb << 2) | wave; // wave-in-batch, 0..255
  const float* Kb = Kmat + (size_t)bb * M1 * KSTRIDE;
  float* eub = eu + bb * KSTRIDE;

  __shared__ __align__(16) float evs[KSTRIDE];
  __shared__ __align__(16) float wpart[4][KSTRIDE];

  // zero the it+1 csum buffer (one block per batch suffices)
  if (rb == 0) {
    for (int j = t; j < KSTRIDE; j += 256) csum_zero[bb * KSTRIDE + j] = 0.f;
  }
  // phase A: ev into LDS
  if (first) {
    for (int j = t; j < KSTRIDE; j += 256) evs[j] = (j < M1) ? 1.0f : 0.f;
  } else {
    for (int j = t; j < KSTRIDE; j += 256) {
      float nu = (j < NPTS) ? MU_PT : ((j == NPTS) ? MU_BIN : 0.f);
      float c = csum_prev[bb * KSTRIDE + j];
      evs[j] = (j < M1) ? (nu / c) : 0.f;
    }
  }
  __syncthreads();

  // phase B: rows
  float4 acc4[6];
#pragma unroll
  for (int k = 0; k < 6; ++k) acc4[k] = make_float4(0.f, 0.f, 0.f, 0.f);

  for (int i = wv; i < M1; i += 256) {
    const float* row = Kb + (size_t)i * KSTRIDE;
    float4 r4[6];
    float dot = 0.f;
#pragma unroll
    for (int k = 0; k < 6; ++k) {
      int j4 = lane + (k << 6);
      if (j4 < KSTRIDE / 4) {
        float4 r = ld4(row + (j4 << 2));
        float4 e = *(const float4*)&evs[j4 << 2];
        r4[k] = r;
        dot += r.x * e.x + r.y * e.y + r.z * e.z + r.w * e.w;
      } else {
        r4[k] = make_float4(0.f, 0.f, 0.f, 0.f);
      }
    }
#pragma unroll
    for (int off = 32; off > 0; off >>= 1) dot += __shfl_xor(dot, off);
    float mu = (i < NPTS) ? MU_PT : MU_BIN;
    float euv = mu / dot;
    if (lane == 0) eub[i] = euv;
#pragma unroll
    for (int k = 0; k < 6; ++k) {
      acc4[k].x += r4[k].x * euv;
      acc4[k].y += r4[k].y * euv;
      acc4[k].z += r4[k].z * euv;
      acc4[k].w += r4[k].w * euv;
    }
  }

  // phase C: combine 4 waves in LDS, then atomics into csum_cur
#pragma unroll
  for (int k = 0; k < 6; ++k) {
    int j4 = lane + (k << 6);
    if (j4 < KSTRIDE / 4) *(float4*)&wpart[wave][j4 << 2] = acc4[k];
  }
  __syncthreads();
  for (int j = t; j < M1; j += 256) {
    float s = wpart[0][j] + wpart[1][j] + wpart[2][j] + wpart[3][j];
    atomicAdd(&csum_cur[bb * KSTRIDE + j], s);
  }
}

// Final ev from last iteration's csum
__global__ void final_ev_kernel(const float* __restrict__ csum,
                                float* __restrict__ ev)
{
  int j = blockIdx.x * 256 + threadIdx.x;
  int bb = blockIdx.y;
  if (j >= M1) return;
  float nu = (j < NPTS) ? MU_PT : MU_BIN;
  ev[bb * KSTRIDE + j] = nu / csum[bb * KSTRIDE + j];
}

// out[b][i][j] = K * eu_i * ev_j * 3000 ; one block per output row (coalesced)
__global__ __launch_bounds__(256) void finalize_kernel(
    const float* __restrict__ Kmat, const float* __restrict__ eu,
    const float* __restrict__ ev, float* __restrict__ out)
{
  int rowid = blockIdx.x;                 // 0 .. BATCH*M1-1
  int b = rowid / M1, i = rowid % M1;
  const float* krow = Kmat + ((size_t)b * M1 + i) * KSTRIDE;
  const float* evb = ev + b * KSTRIDE;
  float* orow = out + (size_t)rowid * M1;
  float scale = eu[b * KSTRIDE + i] * 3000.0f;
  for (int j = threadIdx.x; j < M1; j += 256)
    orow[j] = krow[j] * evb[j] * scale;
}

// ---------------------------------------------------------------------------
extern "C" void kernel_launch(void* const* d_in, const int* in_sizes, int n_in,
                              void* d_out, int out_size, void* d_ws, size_t ws_size,
                              hipStream_t stream)
{
  const float* quer      = (const float*)d_in[0];
  const float* pos_start = (const float*)d_in[1];
  const float* pos_end   = (const float*)d_in[2];
  const float* W1 = (const float*)d_in[3];
  const float* b1 = (const float*)d_in[4];
  const float* W2 = (const float*)d_in[5];
  const float* b2 = (const float*)d_in[6];
  const float* W3 = (const float*)d_in[7];
  const float* b3 = (const float*)d_in[8];
  const float* alpha = (const float*)d_in[9];

  char* ws = (char*)d_ws;
  size_t off = 0;
  auto carve = [&](size_t bytes) -> void* {
    void* p = ws + off;
    off += (bytes + 1023) & ~(size_t)1023;
    return p;
  };
  float* H1   = (float*)carve((size_t)MROWS * 256 * 4);          // 24.6 MB
  float* H2   = (float*)carve((size_t)MROWS * 256 * 4);          // 24.6 MB
  float* K    = (float*)carve((size_t)BATCH * M1 * KSTRIDE * 4); // 72.2 MB
  float* csum[3];
  for (int c = 0; c < 3; ++c) csum[c] = (float*)carve((size_t)BATCH * KSTRIDE * 4);
  float* eu   = (float*)carve((size_t)BATCH * KSTRIDE * 4);
  float* ev   = (float*)carve((size_t)BATCH * KSTRIDE * 4);
  (void)ws_size; (void)in_sizes; (void)n_in; (void)out_size;

  dim3 blk(256);
  // MLP: f1 rows [0,12000) use pos_end; f2 rows [12000,24000) use pos_start
  mlp1_kernel<<<dim3(188, 4), blk, 0, stream>>>(quer, pos_end, pos_start, W1, b1, H1);
  gemm_bias_kernel<1><<<dim3(188, 4), blk, 0, stream>>>(H1, W2, b2, H2, MROWS);
  gemm_bias_kernel<0><<<dim3(188, 4), blk, 0, stream>>>(H2, W3, b3, H1, MROWS);
  // scores -> K (exp domain), bins + pads + csum[0] zero
  scores_kernel<<<dim3(12, 24, 8), blk, 0, stream>>>(H1, K);
  bins_kernel<<<dim3((BATCH * KSTRIDE + 255) / 256), blk, 0, stream>>>(K, alpha, csum[0]);
  // sinkhorn: 50 fused dispatches, triple-buffered csum
  for (int it = 0; it < ITERS; ++it) {
    float* prev = csum[(it + 2) % 3];
    float* cur  = csum[it % 3];
    float* znxt = csum[(it + 1) % 3];
    sink_iter_kernel<<<dim3(512), blk, 0, stream>>>(K, prev, cur, znxt, eu, it == 0 ? 1 : 0);
  }
  final_ev_kernel<<<dim3(6, 8), blk, 0, stream>>>(csum[(ITERS - 1) % 3], ev);
  // output
  finalize_kernel<<<dim3(BATCH * M1), blk, 0, stream>>>(K, eu, ev, (float*)d_out);
}

// Round 4
// 1012.619 us; speedup vs baseline: 1.3339x; 1.2529x over previous
//
#include <hip/hip_runtime.h>
#include <hip/hip_fp16.h>

// Problem constants
#define BATCH 8
#define NPTS 1500         // N
#define DIM 256           // D
#define M1 1501           // NPTS+1 (couplings dim)
#define KH 1536           // padded row stride for fp16 K matrix (24*64 halves)
#define MROWS 24000       // 2*B*N rows through the MLP
#define ITERS 50
#define MU_PT (1.0f / 3000.0f)
#define MU_BIN 0.5f

__device__ __forceinline__ float4 ld4(const float* p){ return *(const float4*)p; }

// ---------------------------------------------------------------------------
// GEMM 1: H1 = relu([quer | pos_end or pos_start] @ W1 + b1)
// M=24000, K=512, N=256.  BM=128, BN=64, BK=16, 256 thr, 8x4 micro-tile.
// ---------------------------------------------------------------------------
__global__ __launch_bounds__(256) void mlp1_kernel(
    const float* __restrict__ quer, const float* __restrict__ pos_end,
    const float* __restrict__ pos_start, const float* __restrict__ W1,
    const float* __restrict__ b1, float* __restrict__ H)
{
  __shared__ float As[16][128];
  __shared__ float Bs[16][64];
  const int t = threadIdx.x;
  const int tm = t & 15, tn = t >> 4;
  const int m0 = blockIdx.x * 128, n0 = blockIdx.y * 64;
  float acc[8][4];
#pragma unroll
  for (int i = 0; i < 8; ++i)
#pragma unroll
    for (int j = 0; j < 4; ++j) acc[i][j] = 0.f;

  for (int kt = 0; kt < 512; kt += 16) {
#pragma unroll
    for (int it = 0; it < 2; ++it) {
      int s = t + it * 256;
      int m = s >> 2, kq = s & 3;
      int row = m0 + m;
      int col = kt + (kq << 2);
      float4 v = make_float4(0.f, 0.f, 0.f, 0.f);
      if (row < MROWS) {
        int r12 = (row < 12000) ? row : row - 12000;
        const float* src;
        if (col < 256) src = quer + (size_t)r12 * 256 + col;
        else src = ((row < 12000) ? pos_end : pos_start) + (size_t)r12 * 256 + (col - 256);
        v = ld4(src);
      }
      int kk = kq << 2;
      As[kk + 0][m] = v.x; As[kk + 1][m] = v.y; As[kk + 2][m] = v.z; As[kk + 3][m] = v.w;
    }
    {
      int kr = t >> 4, nq = t & 15;
      float4 w = ld4(W1 + (size_t)(kt + kr) * 256 + n0 + (nq << 2));
      *(float4*)&Bs[kr][nq << 2] = w;
    }
    __syncthreads();
#pragma unroll
    for (int k = 0; k < 16; ++k) {
      float4 a0 = *(float4*)&As[k][tm << 2];
      float4 a1 = *(float4*)&As[k][64 + (tm << 2)];
      float4 b  = *(float4*)&Bs[k][tn << 2];
      float am[8] = {a0.x, a0.y, a0.z, a0.w, a1.x, a1.y, a1.z, a1.w};
      float bn[4] = {b.x, b.y, b.z, b.w};
#pragma unroll
      for (int i = 0; i < 8; ++i)
#pragma unroll
        for (int j = 0; j < 4; ++j) acc[i][j] += am[i] * bn[j];
    }
    __syncthreads();
  }
  float4 bb = ld4(b1 + n0 + (tn << 2));
  float bn[4] = {bb.x, bb.y, bb.z, bb.w};
#pragma unroll
  for (int i = 0; i < 8; ++i) {
    int row = m0 + ((i < 4) ? ((tm << 2) + i) : (64 + (tm << 2) + i - 4));
    if (row < MROWS) {
      float4 o;
      o.x = fmaxf(acc[i][0] + bn[0], 0.f);
      o.y = fmaxf(acc[i][1] + bn[1], 0.f);
      o.z = fmaxf(acc[i][2] + bn[2], 0.f);
      o.w = fmaxf(acc[i][3] + bn[3], 0.f);
      *(float4*)&H[(size_t)row * 256 + n0 + (tn << 2)] = o;
    }
  }
}

// ---------------------------------------------------------------------------
// GEMM: out = act(A @ W + b), A:[M][256], W:[256][256]
// ---------------------------------------------------------------------------
template<int RELU>
__global__ __launch_bounds__(256) void gemm_bias_kernel(
    const float* __restrict__ A, const float* __restrict__ W,
    const float* __restrict__ bias, float* __restrict__ out, int M)
{
  __shared__ float As[16][128];
  __shared__ float Bs[16][64];
  const int t = threadIdx.x;
  const int tm = t & 15, tn = t >> 4;
  const int m0 = blockIdx.x * 128, n0 = blockIdx.y * 64;
  float acc[8][4];
#pragma unroll
  for (int i = 0; i < 8; ++i)
#pragma unroll
    for (int j = 0; j < 4; ++j) acc[i][j] = 0.f;

  for (int kt = 0; kt < 256; kt += 16) {
#pragma unroll
    for (int it = 0; it < 2; ++it) {
      int s = t + it * 256;
      int m = s >> 2, kq = s & 3;
      int row = m0 + m;
      int col = kt + (kq << 2);
      float4 v = make_float4(0.f, 0.f, 0.f, 0.f);
      if (row < M) v = ld4(A + (size_t)row * 256 + col);
      int kk = kq << 2;
      As[kk + 0][m] = v.x; As[kk + 1][m] = v.y; As[kk + 2][m] = v.z; As[kk + 3][m] = v.w;
    }
    {
      int kr = t >> 4, nq = t & 15;
      float4 w = ld4(W + (size_t)(kt + kr) * 256 + n0 + (nq << 2));
      *(float4*)&Bs[kr][nq << 2] = w;
    }
    __syncthreads();
#pragma unroll
    for (int k = 0; k < 16; ++k) {
      float4 a0 = *(float4*)&As[k][tm << 2];
      float4 a1 = *(float4*)&As[k][64 + (tm << 2)];
      float4 b  = *(float4*)&Bs[k][tn << 2];
      float am[8] = {a0.x, a0.y, a0.z, a0.w, a1.x, a1.y, a1.z, a1.w};
      float bn[4] = {b.x, b.y, b.z, b.w};
#pragma unroll
      for (int i = 0; i < 8; ++i)
#pragma unroll
        for (int j = 0; j < 4; ++j) acc[i][j] += am[i] * bn[j];
    }
    __syncthreads();
  }
  float4 bb = ld4(bias + n0 + (tn << 2));
  float bn[4] = {bb.x, bb.y, bb.z, bb.w};
#pragma unroll
  for (int i = 0; i < 8; ++i) {
    int row = m0 + ((i < 4) ? ((tm << 2) + i) : (64 + (tm << 2) + i - 4));
    if (row < M) {
      float4 o;
      o.x = acc[i][0] + bn[0]; o.y = acc[i][1] + bn[1];
      o.z = acc[i][2] + bn[2]; o.w = acc[i][3] + bn[3];
      if (RELU) { o.x = fmaxf(o.x, 0.f); o.y = fmaxf(o.y, 0.f); o.z = fmaxf(o.z, 0.f); o.w = fmaxf(o.w, 0.f); }
      *(float4*)&out[(size_t)row * 256 + n0 + (tn << 2)] = o;
    }
  }
}

// ---------------------------------------------------------------------------
// Scores: Kh[b][i][j] = fp16(exp(f1_i . f2_j / 16)), diag->0, pads->0.
// F holds f1 rows [0,12000), f2 rows [12000,24000).
// Grid (12, 24, 8): covers gi < 1536 (guarded to NPTS), gj < 1536 (=KH, pads
// written as zero; bin col at gj==NPTS is overwritten later by bins_kernel).
// ---------------------------------------------------------------------------
__global__ __launch_bounds__(256) void scores_kernel(
    const float* __restrict__ F, __half* __restrict__ Kh)
{
  __shared__ float As[16][128];
  __shared__ float Bs[16][64];
  const int t = threadIdx.x;
  const int tm = t & 15, tn = t >> 4;
  const int b = blockIdx.z;
  const int m0 = blockIdx.x * 128, n0 = blockIdx.y * 64;
  const float* F1 = F + (size_t)b * NPTS * 256;
  const float* F2 = F + (size_t)(12000 + b * NPTS) * 256;
  __half* Kb = Kh + (size_t)b * M1 * KH;
  float acc[8][4];
#pragma unroll
  for (int i = 0; i < 8; ++i)
#pragma unroll
    for (int j = 0; j < 4; ++j) acc[i][j] = 0.f;

  for (int kt = 0; kt < 256; kt += 16) {
#pragma unroll
    for (int it = 0; it < 2; ++it) {
      int s = t + it * 256;
      int m = s >> 2, kq = s & 3;
      int row = m0 + m;
      float4 v = make_float4(0.f, 0.f, 0.f, 0.f);
      if (row < NPTS) v = ld4(F1 + (size_t)row * 256 + kt + (kq << 2));
      int kk = kq << 2;
      As[kk + 0][m] = v.x; As[kk + 1][m] = v.y; As[kk + 2][m] = v.z; As[kk + 3][m] = v.w;
    }
    {
      int n = t >> 2, kq = t & 3;
      float4 v = make_float4(0.f, 0.f, 0.f, 0.f);
      if (n0 + n < NPTS) v = ld4(F2 + (size_t)(n0 + n) * 256 + kt + (kq << 2));
      int kk = kq << 2;
      Bs[kk + 0][n] = v.x; Bs[kk + 1][n] = v.y; Bs[kk + 2][n] = v.z; Bs[kk + 3][n] = v.w;
    }
    __syncthreads();
#pragma unroll
    for (int k = 0; k < 16; ++k) {
      float4 a0 = *(float4*)&As[k][tm << 2];
      float4 a1 = *(float4*)&As[k][64 + (tm << 2)];
      float4 b4 = *(float4*)&Bs[k][tn << 2];
      float am[8] = {a0.x, a0.y, a0.z, a0.w, a1.x, a1.y, a1.z, a1.w};
      float bn[4] = {b4.x, b4.y, b4.z, b4.w};
#pragma unroll
      for (int i = 0; i < 8; ++i)
#pragma unroll
        for (int j = 0; j < 4; ++j) acc[i][j] += am[i] * bn[j];
    }
    __syncthreads();
  }
#pragma unroll
  for (int i = 0; i < 8; ++i) {
    int gi = m0 + ((i < 4) ? ((tm << 2) + i) : (64 + (tm << 2) + i - 4));
    if (gi < NPTS) {
      int gj0 = n0 + (tn << 2);
      float v[4];
#pragma unroll
      for (int j = 0; j < 4; ++j) {
        int gj = gj0 + j;
        v[j] = (gj < NPTS && gj != gi) ? expf(acc[i][j] * 0.0625f) : 0.f;
      }
      __half2 h0 = __floats2half2_rn(v[0], v[1]);
      __half2 h1 = __floats2half2_rn(v[2], v[3]);
      union { __half2 h[2]; uint2 u; } U; U.h[0] = h0; U.h[1] = h1;
      *(uint2*)&Kb[(size_t)gi * KH + gj0] = U.u;   // 8B aligned store
    }
  }
}

// ---------------------------------------------------------------------------
// bins: bin row/col = fp16(exp(alpha)); zero bin-row pads; zero csum0.
// Grid over BATCH*KH.
// ---------------------------------------------------------------------------
__global__ void bins_kernel(__half* __restrict__ Kh, const float* __restrict__ palpha,
                            float* __restrict__ csum0)
{
  int gid = blockIdx.x * 256 + threadIdx.x;
  if (gid >= BATCH * KH) return;
  int b = gid / KH, x = gid % KH;
  __half He = __float2half(expf(palpha[0]));
  __half* Kb = Kh + (size_t)b * M1 * KH;
  csum0[gid] = 0.f;
  if (x < M1) {
    Kb[(size_t)NPTS * KH + x] = He;   // bin row
    Kb[(size_t)x * KH + NPTS] = He;   // bin col (corner included)
  } else {
    Kb[(size_t)NPTS * KH + x] = __float2half(0.f); // bin-row pads
  }
}

// ---------------------------------------------------------------------------
// Fused Sinkhorn iteration (fp16 K), ONE dispatch per iteration.
// bb = blockIdx % 8  -> XCD affinity (round-robin heuristic): each batch's
// 4.5 MB K slab stays mostly in one XCD's 4 MB L2.
// 64 blocks/batch, wave wv handles rows i = wv, wv+256, ...
//  A) ev[j] = nu_j / csum_prev[j] into LDS; block rb==0 zeros csum_zero.
//  B) per row: 3 x 16B half loads -> 24 floats in regs, dot vs LDS ev,
//     eu_i = mu_i/dot, col partials acc += r * eu_i.
//  C) 4-wave LDS combine, atomicAdd into csum_cur.
// ---------------------------------------------------------------------------
__global__ __launch_bounds__(256) void sink_iter_kernel(
    const __half* __restrict__ Kh,
    const float* __restrict__ csum_prev,
    float* __restrict__ csum_cur,
    float* __restrict__ csum_zero,
    float* __restrict__ eu, int first)
{
  const int t = threadIdx.x;
  const int wave = t >> 6, lane = t & 63;
  const int bb = blockIdx.x & 7;   // batch == XCD (heuristic)
  const int rb = blockIdx.x >> 3;  // block-in-batch, 0..63
  const int wv = (rb << 2) | wave; // wave-in-batch, 0..255
  const __half* Kb = Kh + (size_t)bb * M1 * KH;
  float* eub = eu + bb * KH;

  __shared__ __align__(16) float evs[KH];
  __shared__ __align__(16) float wpart[4][KH];

  if (rb == 0) {
    for (int j = t; j < KH; j += 256) csum_zero[bb * KH + j] = 0.f;
  }
  // phase A: ev into LDS
  if (first) {
    for (int j = t; j < KH; j += 256) evs[j] = (j < M1) ? 1.0f : 0.f;
  } else {
    for (int j = t; j < KH; j += 256) {
      float nu = (j < NPTS) ? MU_PT : ((j == NPTS) ? MU_BIN : 0.f);
      evs[j] = (j < M1) ? (nu / csum_prev[bb * KH + j]) : 0.f;
    }
  }
  __syncthreads();

  // phase B: rows
  float acc[24];
#pragma unroll
  for (int k = 0; k < 24; ++k) acc[k] = 0.f;

  for (int i = wv; i < M1; i += 256) {
    const __half* row = Kb + (size_t)i * KH;
    float r[24];
    float dot = 0.f;
#pragma unroll
    for (int k = 0; k < 3; ++k) {
      int c = lane + (k << 6);                 // chunk of 8 halves
      union { uint4 u; __half2 h[4]; } U;
      U.u = *(const uint4*)(row + (c << 3));   // 16B load
#pragma unroll
      for (int m = 0; m < 4; ++m) {
        float2 f = __half22float2(U.h[m]);
        r[k * 8 + 2 * m]     = f.x;
        r[k * 8 + 2 * m + 1] = f.y;
      }
      float4 e0 = *(const float4*)&evs[(c << 3)];
      float4 e1 = *(const float4*)&evs[(c << 3) + 4];
      dot += r[k*8+0]*e0.x + r[k*8+1]*e0.y + r[k*8+2]*e0.z + r[k*8+3]*e0.w
           + r[k*8+4]*e1.x + r[k*8+5]*e1.y + r[k*8+6]*e1.z + r[k*8+7]*e1.w;
    }
#pragma unroll
    for (int off = 32; off > 0; off >>= 1) dot += __shfl_xor(dot, off);
    float mu = (i < NPTS) ? MU_PT : MU_BIN;
    float euv = mu / dot;
    if (lane == 0) eub[i] = euv;
#pragma unroll
    for (int k = 0; k < 24; ++k) acc[k] += r[k] * euv;
  }

  // phase C: combine 4 waves in LDS, atomics into csum_cur
#pragma unroll
  for (int k = 0; k < 3; ++k) {
    int c = lane + (k << 6);
    float4 a0 = make_float4(acc[k*8+0], acc[k*8+1], acc[k*8+2], acc[k*8+3]);
    float4 a1 = make_float4(acc[k*8+4], acc[k*8+5], acc[k*8+6], acc[k*8+7]);
    *(float4*)&wpart[wave][(c << 3)]     = a0;
    *(float4*)&wpart[wave][(c << 3) + 4] = a1;
  }
  __syncthreads();
  for (int j = t; j < M1; j += 256) {
    float s = wpart[0][j] + wpart[1][j] + wpart[2][j] + wpart[3][j];
    atomicAdd(&csum_cur[bb * KH + j], s);
  }
}

// Final ev from last iteration's csum
__global__ void final_ev_kernel(const float* __restrict__ csum,
                                float* __restrict__ ev)
{
  int j = blockIdx.x * 256 + threadIdx.x;
  int bb = blockIdx.y;
  if (j >= M1) return;
  float nu = (j < NPTS) ? MU_PT : MU_BIN;
  ev[bb * KH + j] = nu / csum[bb * KH + j];
}

// out[b][i][j] = Kh * eu_i * ev_j * 3000 ; one block per output row
__global__ __launch_bounds__(256) void finalize_kernel(
    const __half* __restrict__ Kh, const float* __restrict__ eu,
    const float* __restrict__ ev, float* __restrict__ out)
{
  int rowid = blockIdx.x;                 // 0 .. BATCH*M1-1
  int b = rowid / M1, i = rowid % M1;
  const __half* krow = Kh + ((size_t)b * M1 + i) * KH;
  const float* evb = ev + b * KH;
  float* orow = out + (size_t)rowid * M1;
  float scale = eu[b * KH + i] * 3000.0f;
  for (int j = threadIdx.x; j < M1; j += 256)
    orow[j] = __half2float(krow[j]) * evb[j] * scale;
}

// ---------------------------------------------------------------------------
extern "C" void kernel_launch(void* const* d_in, const int* in_sizes, int n_in,
                              void* d_out, int out_size, void* d_ws, size_t ws_size,
                              hipStream_t stream)
{
  const float* quer      = (const float*)d_in[0];
  const float* pos_start = (const float*)d_in[1];
  const float* pos_end   = (const float*)d_in[2];
  const float* W1 = (const float*)d_in[3];
  const float* b1 = (const float*)d_in[4];
  const float* W2 = (const float*)d_in[5];
  const float* b2 = (const float*)d_in[6];
  const float* W3 = (const float*)d_in[7];
  const float* b3 = (const float*)d_in[8];
  const float* alpha = (const float*)d_in[9];

  char* ws = (char*)d_ws;
  size_t off = 0;
  auto carve = [&](size_t bytes) -> void* {
    void* p = ws + off;
    off += (bytes + 1023) & ~(size_t)1023;
    return p;
  };
  float*  H1 = (float*)carve((size_t)MROWS * 256 * 4);            // 24.6 MB
  float*  H2 = (float*)carve((size_t)MROWS * 256 * 4);            // 24.6 MB
  __half* Kh = (__half*)carve((size_t)BATCH * M1 * KH * 2);       // 36.9 MB
  float* csum[3];
  for (int c = 0; c < 3; ++c) csum[c] = (float*)carve((size_t)BATCH * KH * 4);
  float* eu = (float*)carve((size_t)BATCH * KH * 4);
  float* ev = (float*)carve((size_t)BATCH * KH * 4);
  (void)ws_size; (void)in_sizes; (void)n_in; (void)out_size;

  dim3 blk(256);
  // MLP: f1 rows [0,12000) use pos_end; f2 rows [12000,24000) use pos_start
  mlp1_kernel<<<dim3(188, 4), blk, 0, stream>>>(quer, pos_end, pos_start, W1, b1, H1);
  gemm_bias_kernel<1><<<dim3(188, 4), blk, 0, stream>>>(H1, W2, b2, H2, MROWS);
  gemm_bias_kernel<0><<<dim3(188, 4), blk, 0, stream>>>(H2, W3, b3, H1, MROWS);
  // scores -> Kh (fp16 exp domain, pads zeroed), bins + csum[0] zero
  scores_kernel<<<dim3(12, 24, 8), blk, 0, stream>>>(H1, Kh);
  bins_kernel<<<dim3((BATCH * KH + 255) / 256), blk, 0, stream>>>(Kh, alpha, csum[0]);
  // sinkhorn: 50 fused dispatches, triple-buffered csum
  for (int it = 0; it < ITERS; ++it) {
    float* prev = csum[(it + 2) % 3];
    float* cur  = csum[it % 3];
    float* znxt = csum[(it + 1) % 3];
    sink_iter_kernel<<<dim3(512), blk, 0, stream>>>(Kh, prev, cur, znxt, eu, it == 0 ? 1 : 0);
  }
  final_ev_kernel<<<dim3(6, 8), blk, 0, stream>>>(csum[(ITERS - 1) % 3], ev);
  // output
  finalize_kernel<<<dim3(BATCH * M1), blk, 0, stream>>>(Kh, eu, ev, (float*)d_out);
}